// Round 22
// baseline (49.975 us; speedup 1.0000x reference)
//
#include <hip/hip_runtime.h>

// out[b] = sum_g exp(-(||x_b||^2+||c_g||^2-2 x_b.c_g)/2) * w[g]
// B=16384, G=8192, D=64 fp32.
// v22 = v21 (single-pass f16 MFMA, A pre-scaled by log2e, cn in MFMA
// C-operand, cw prefetch) MINUS E/O acc double-buffer, PLUS a 4th wave:
// single acc set frees 32 AGPRs (~119 regs), __launch_bounds__(256,4),
// GSPLIT=16 -> grid 1024 = 4 blocks/CU. Tests the last hypothesis: the
// ~50% issue-dead time is latency with too little TLP; 4 waves/SIMD at
// independent phases interleave matrix/trans/VALU across waves instead
// of E/O's intra-wave overlap. If neutral: v21 is the ceiling.

typedef __attribute__((ext_vector_type(8))) _Float16 half8v;
typedef __attribute__((ext_vector_type(16))) float f32x16;
typedef unsigned short u16;
typedef unsigned int u32;

#define L2E   1.4426950408889634f
#define NHL2E 0.72134752044448170f   // log2(e)/2
#define GP 16                        // col parts: 512 cols = 16 tiles each

#define MFMA(a,b,c) __builtin_amdgcn_mfma_f32_32x32x16_f16(a,b,c,0,0,0)

// ---- one-time: C [G][64] fp32 -> f16 in MFMA fragment order + (cn,w);
// also zeroes out[] (32768 threads >= B; replaces the memset dispatch). ----
__global__ __launch_bounds__(256)
void convert_C(const float* __restrict__ C, const float* __restrict__ W,
               _Float16* __restrict__ Cf, float2* __restrict__ cw,
               float* __restrict__ out, int G, int B){
  int idx = blockIdx.x*256 + threadIdx.x;
  if (idx < B) out[idx] = 0.f;
  int g = idx >> 2, f = idx & 3;
  if (g >= G) return;
  const float* row = C + (size_t)g*64 + f*16;
  int cg = g >> 5, cl = g & 31;
  float norm = 0.f;
  _Float16 hv[16];
  #pragma unroll
  for (int q=0; q<4; q++){
    float4 v = *(const float4*)(row + q*4);
    float xv[4] = {v.x, v.y, v.z, v.w};
    #pragma unroll
    for (int e=0; e<4; e++){
      float x = xv[e];
      norm = fmaf(x, x, norm);
      hv[q*4+e] = (_Float16)x;       // B unscaled; A carries L2E
    }
  }
  norm += __shfl_xor(norm, 1);
  norm += __shfl_xor(norm, 2);
  size_t u = ((size_t)(cg*4 + f)*64 + cl)*8;
  *(half8v*)(Cf + u)       = *(half8v*)hv;        // h=0 (k 0..7)
  *(half8v*)(Cf + u + 256) = *(half8v*)(hv + 8);  // h=1 (k 8..15)
  if (f == 0) cw[g] = make_float2(-NHL2E*norm, W[g]);
}

__global__ __launch_bounds__(256, 4)
void rbf_mfma(const float* __restrict__ X, const _Float16* __restrict__ Cf,
              const float2* __restrict__ cw, float* __restrict__ out){
  const int tid = threadIdx.x;
  const int l  = tid & 63;
  const int cl = l & 31;
  const int h  = l >> 5;
  const int w  = tid >> 6;
  const int b  = blockIdx.x;
  const int gp = b & 15;               // 4 waves share gp -> L1/L2 B-sharing
  const int rows0 = (b >> 4) * 256 + w * 64;
  const int t0 = gp * 16;              // 16 tiles of 32 cols per part

  // ---- A: 64 rows (2 rowfrags), PRE-SCALED by L2E, f16 in regs + norms ----
  half8v af[2][4];
  float xn[2];
  #pragma unroll
  for (int rf=0; rf<2; rf++){
    const float* xr = X + (size_t)(rows0 + rf*32 + cl)*64;
    float s = 0.f;
    #pragma unroll
    for (int f=0; f<4; f++){
      float4 v0 = *(const float4*)(xr + f*16 + h*8);
      float4 v1 = *(const float4*)(xr + f*16 + h*8 + 4);
      float xv[8] = {v0.x,v0.y,v0.z,v0.w,v1.x,v1.y,v1.z,v1.w};
      _Float16 hv[8];
      #pragma unroll
      for (int e=0;e<8;e++){
        float x = xv[e];
        s = fmaf(x, x, s);
        hv[e] = (_Float16)(x * L2E);   // scale folded into A
      }
      af[rf][f] = *(half8v*)hv;
    }
    s += __shfl_xor(s, 32);
    xn[rf] = -NHL2E * s;
  }

  // B stream: byte addr = T*4096 + f*1024 + l*16 (T = global col-tile)
  const char* baseF = (const char*)Cf + (size_t)l*16;
  const float2* cwp = cw + cl;

  half8v bf[2];
  bf[0] = *(const half8v*)(baseF + (size_t)t0*4096);   // (t0, f=0)

  float racc0[16], racc1[16];
  #pragma unroll
  for (int r=0;r<16;r++){ racc0[r]=0.f; racc1[r]=0.f; }

  float2 cwv = cwp[t0*32];             // (cn, w) for tile t0

  #pragma unroll 1
  for (int ti = 0; ti < 16; ++ti){
    const int T  = t0 + ti;
    const int TN = (ti < 15) ? T + 1 : t0;     // tail prefetch wraps (dead)

    // C-operand init with cn splat (acc exits MFMA = L2E*dot + cn)
    f32x16 a0, a1;
    #pragma unroll
    for (int r=0;r<16;++r){ a0[r] = cwv.x; a1[r] = cwv.x; }

    #pragma unroll
    for (int f=0; f<4; ++f){
      const int p = f & 1, q = p ^ 1;
      const int nf = (f + 1) & 3;
      const int nt = (f == 3) ? TN : T;
      bf[q] = *(const half8v*)(baseF + (size_t)nt*4096 + (size_t)nf*1024);
      a0 = MFMA(af[0][f], bf[p], a0);
      a1 = MFMA(af[1][f], bf[p], a1);
    }

    // EPI: racc += exp2(acc) * w ; then rotate cw to next tile
    const float wgt = cwv.y;
    #pragma unroll
    for (int r=0;r<16;++r){
      racc0[r] = fmaf(__builtin_amdgcn_exp2f(a0[r]), wgt, racc0[r]);
      racc1[r] = fmaf(__builtin_amdgcn_exp2f(a1[r]), wgt, racc1[r]);
    }
    cwv = cwp[TN*32];
  }

  // ---- reduce over 32 col-lanes, fold 2^xn, one atomic per row ----
  #pragma unroll
  for (int rf=0; rf<2; rf++){
    #pragma unroll
    for (int r=0;r<16;r++){
      float v = rf ? racc1[r] : racc0[r];
      v += __shfl_xor(v, 1);
      v += __shfl_xor(v, 2);
      v += __shfl_xor(v, 4);
      v += __shfl_xor(v, 8);
      v += __shfl_xor(v, 16);
      const int rit = (r&3) + 8*(r>>2) + 4*h;
      const float xnv = __shfl(xn[rf], rit);
      if (cl == 0)
        atomicAdd(&out[rows0 + rf*32 + rit], v * __builtin_amdgcn_exp2f(xnv));
    }
  }
}

extern "C" void kernel_launch(void* const* d_in, const int* in_sizes, int n_in,
                              void* d_out, int out_size, void* d_ws, size_t ws_size,
                              hipStream_t stream) {
  const float* X = (const float*)d_in[0];   // [B,64]
  const float* C = (const float*)d_in[1];   // [G,64]
  const float* W = (const float*)d_in[2];   // [G]
  float* out = (float*)d_out;               // [B]
  const int B = in_sizes[0] / 64;
  const int G = in_sizes[2];

  _Float16* Cf = (_Float16*)d_ws;                // 1 MB, fragment-ordered
  float2* cw = (float2*)(Cf + (size_t)G*64);     // 64 KB

  convert_C<<<(G*4)/256, 256, 0, stream>>>(C, W, Cf, cw, out, G, B);
  rbf_mfma<<<(B/256)*GP, 256, 0, stream>>>(X, Cf, cw, out);
}

// Round 23
// 44.037 us; speedup vs baseline: 1.1348x; 1.1348x over previous
//
#include <hip/hip_runtime.h>

// out[b] = sum_g exp(-(||x_b||^2+||c_g||^2-2 x_b.c_g)/2) * w[g]
// B=16384, G=8192, D=64 fp32.
// v23 = FINAL = v21 verbatim (best: headline 44.0us, kernel 39.7us, absmax
// 1.455e-11 vs 5.8e-11 thr). Single-pass f16 MFMA (A pre-scaled by log2e,
// cn folded into the MFMA C-operand), reg-streamed B depth-1 ping-pong,
// E/O acc sets with EPI (exp2+fma only) hand-interleaved, GSPLIT=12,
// __launch_bounds__(256,3), convert_C zeroes out (no memset dispatch).
// Exhausted/falsified: more TLP (R16/R22), deeper prefetch (R7/R8),
// LDS-resident B (R18), P/C wave split (R13/R14), sched_group_barrier
// (R11, corrupts), exp screening (R17), poly-exp on VALU (R19).

typedef __attribute__((ext_vector_type(8))) _Float16 half8v;
typedef __attribute__((ext_vector_type(16))) float f32x16;
typedef unsigned short u16;
typedef unsigned int u32;

#define L2E   1.4426950408889634f
#define NHL2E 0.72134752044448170f   // log2(e)/2
#define GP 12                        // col parts: gp<4 -> 22 tiles, else 21

#define MFMA(a,b,c) __builtin_amdgcn_mfma_f32_32x32x16_f16(a,b,c,0,0,0)

// ---- one-time: C [G][64] fp32 -> f16 in MFMA fragment order + (cn,w);
// also zeroes out[] (32768 threads >= B; replaces the memset dispatch). ----
__global__ __launch_bounds__(256)
void convert_C(const float* __restrict__ C, const float* __restrict__ W,
               _Float16* __restrict__ Cf, float2* __restrict__ cw,
               float* __restrict__ out, int G, int B){
  int idx = blockIdx.x*256 + threadIdx.x;
  if (idx < B) out[idx] = 0.f;
  int g = idx >> 2, f = idx & 3;
  if (g >= G) return;
  const float* row = C + (size_t)g*64 + f*16;
  int cg = g >> 5, cl = g & 31;
  float norm = 0.f;
  _Float16 hv[16];
  #pragma unroll
  for (int q=0; q<4; q++){
    float4 v = *(const float4*)(row + q*4);
    float xv[4] = {v.x, v.y, v.z, v.w};
    #pragma unroll
    for (int e=0; e<4; e++){
      float x = xv[e];
      norm = fmaf(x, x, norm);
      hv[q*4+e] = (_Float16)x;       // RNE f32->f16 (B unscaled; A carries L2E)
    }
  }
  norm += __shfl_xor(norm, 1);       // reduce over the 4 f-lanes of this g
  norm += __shfl_xor(norm, 2);
  size_t u = ((size_t)(cg*4 + f)*64 + cl)*8;
  *(half8v*)(Cf + u)       = *(half8v*)hv;        // h=0 (k 0..7)
  *(half8v*)(Cf + u + 256) = *(half8v*)(hv + 8);  // h=1 (k 8..15)
  if (f == 0) cw[g] = make_float2(-NHL2E*norm, W[g]);
}

__global__ __launch_bounds__(256, 3)
void rbf_mfma(const float* __restrict__ X, const _Float16* __restrict__ Cf,
              const float2* __restrict__ cw, float* __restrict__ out){
  const int tid = threadIdx.x;
  const int l  = tid & 63;
  const int cl = l & 31;
  const int h  = l >> 5;
  const int w  = tid >> 6;
  const int b  = blockIdx.x;
  const int gp = b % GP;               // 4 waves share gp -> L1/L2 B-sharing
  const int rows0 = (b / GP) * 256 + w * 64;

  // global col-tile range for this part (256 tiles of 32 cols over G)
  const int t0  = gp * 21 + (gp < 4 ? gp : 4);
  const int ntl = (gp < 4) ? 22 : 21;

  // ---- A: 64 rows (2 rowfrags), PRE-SCALED by L2E, f16 in regs + norms ----
  half8v af[2][4];
  float xn[2];
  #pragma unroll
  for (int rf=0; rf<2; rf++){
    const float* xr = X + (size_t)(rows0 + rf*32 + cl)*64;
    float s = 0.f;
    #pragma unroll
    for (int f=0; f<4; f++){
      float4 v0 = *(const float4*)(xr + f*16 + h*8);
      float4 v1 = *(const float4*)(xr + f*16 + h*8 + 4);
      float xv[8] = {v0.x,v0.y,v0.z,v0.w,v1.x,v1.y,v1.z,v1.w};
      _Float16 hv[8];
      #pragma unroll
      for (int e=0;e<8;e++){
        float x = xv[e];
        s = fmaf(x, x, s);
        hv[e] = (_Float16)(x * L2E);   // scale folded into A
      }
      af[rf][f] = *(half8v*)hv;
    }
    s += __shfl_xor(s, 32);
    xn[rf] = -NHL2E * s;
  }

  // B stream: byte addr = T*4096 + f*1024 + l*16 (T = global col-tile)
  const char* baseF = (const char*)Cf + (size_t)l*16;
  const float2* cwp = cw + cl;

  half8v bf[2];
  bf[0] = *(const half8v*)(baseF + (size_t)t0*4096);   // (t0, f=0)

  float racc0[16], racc1[16];
  #pragma unroll
  for (int r=0;r<16;r++){ racc0[r]=0.f; racc1[r]=0.f; }

  f32x16 aE0, aE1, aO0, aO1;
  float2 cwE, cwO;

  // one epilogue element: acc already holds L2E*dot + cn
  #define EPIX(P, R, CWV, RACC)                                             \
    RACC[R] = fmaf(__builtin_amdgcn_exp2f(P[R]), CWV.y, RACC[R])

  // tile T: C-init from CWC.x (cn splat), 8 MFMA, EPI of prev tile (CWP.y)
  // interleaved; B prefetch toward TN; at end reload CWP <- cw(TN) (next
  // tile's cw; for the final tile TN=t0, value dead).
  #define TILE(T, TN, C0, C1, P0, P1, CWC, CWP, DO_EPI) do {                \
    const int t_ = (T), tn_ = (TN);                                         \
    _Pragma("unroll")                                                       \
    for (int r=0;r<16;++r){ C0[r] = CWC.x; C1[r] = CWC.x; }                 \
    _Pragma("unroll")                                                       \
    for (int f=0; f<4; ++f){                                                \
      const int p = f & 1, q = p ^ 1;                                       \
      const int nf = (f + 1) & 3;                                           \
      const int nt = (f == 3) ? tn_ : t_;                                   \
      bf[q] = *(const half8v*)(baseF + (size_t)nt*4096 + (size_t)nf*1024);  \
      C0 = MFMA(af[0][f], bf[p], C0);                                       \
      if (DO_EPI){                                                          \
        EPIX(P0, f*4+0, CWP, racc0); EPIX(P1, f*4+0, CWP, racc1);           \
        EPIX(P0, f*4+1, CWP, racc0); EPIX(P1, f*4+1, CWP, racc1);           \
      }                                                                     \
      C1 = MFMA(af[1][f], bf[p], C1);                                       \
      if (DO_EPI){                                                          \
        EPIX(P0, f*4+2, CWP, racc0); EPIX(P1, f*4+2, CWP, racc1);           \
        EPIX(P0, f*4+3, CWP, racc0); EPIX(P1, f*4+3, CWP, racc1);           \
      }                                                                     \
    }                                                                       \
    CWP = cwp[tn_*32];                 /* prefetch next tile's (cn,w) */    \
  } while(0)

  // prologue: load cw(t0); tile t0 (even slot), no EPI; end-load cwO=cw(t0+1)
  cwE = cwp[t0*32];
  TILE(t0, t0+1, aE0, aE1, aO0, aO1, cwE, cwO, 0);
  int ti = 1;
  #pragma unroll 1
  for (; ti + 1 < ntl; ti += 2){
    const int To = t0 + ti, Te = t0 + ti + 1;
    const int TnO = Te;                            // next after odd tile
    const int TnE = (ti + 2 < ntl) ? Te + 1 : t0;  // wrap: value dead
    TILE(To, TnO, aO0, aO1, aE0, aE1, cwO, cwE, 1);
    TILE(Te, TnE, aE0, aE1, aO0, aO1, cwE, cwO, 1);
  }
  if (ti < ntl){
    // ntl even: one final odd tile, then flush both
    TILE(t0+ti, t0, aO0, aO1, aE0, aE1, cwO, cwE, 1);
    #pragma unroll
    for (int r=0;r<16;++r){ EPIX(aO0, r, cwO, racc0); EPIX(aO1, r, cwO, racc1); }
  } else {
    // ntl odd: flush the last even tile
    #pragma unroll
    for (int r=0;r<16;++r){ EPIX(aE0, r, cwE, racc0); EPIX(aE1, r, cwE, racc1); }
  }
  #undef TILE
  #undef EPIX

  // ---- reduce over 32 col-lanes, fold 2^xn, one atomic per row ----
  #pragma unroll
  for (int rf=0; rf<2; rf++){
    #pragma unroll
    for (int r=0;r<16;r++){
      float v = rf ? racc1[r] : racc0[r];
      v += __shfl_xor(v, 1);
      v += __shfl_xor(v, 2);
      v += __shfl_xor(v, 4);
      v += __shfl_xor(v, 8);
      v += __shfl_xor(v, 16);
      const int rit = (r&3) + 8*(r>>2) + 4*h;
      const float xnv = __shfl(xn[rf], rit);
      if (cl == 0)
        atomicAdd(&out[rows0 + rf*32 + rit], v * __builtin_amdgcn_exp2f(xnv));
    }
  }
}

extern "C" void kernel_launch(void* const* d_in, const int* in_sizes, int n_in,
                              void* d_out, int out_size, void* d_ws, size_t ws_size,
                              hipStream_t stream) {
  const float* X = (const float*)d_in[0];   // [B,64]
  const float* C = (const float*)d_in[1];   // [G,64]
  const float* W = (const float*)d_in[2];   // [G]
  float* out = (float*)d_out;               // [B]
  const int B = in_sizes[0] / 64;
  const int G = in_sizes[2];

  _Float16* Cf = (_Float16*)d_ws;                // 1 MB, fragment-ordered
  float2* cw = (float2*)(Cf + (size_t)G*64);     // 64 KB

  convert_C<<<(G*4)/256, 256, 0, stream>>>(C, W, Cf, cw, out, G, B);
  rbf_mfma<<<(B/256)*GP, 256, 0, stream>>>(X, Cf, cw, out);
}